// Round 8
// baseline (245.576 us; speedup 1.0000x reference)
//
#include <hip/hip_runtime.h>
#include <math.h>

// LearnableProjector: P[u,v] = a[u]*a[v]*sum_{j in common items} t[j];
// per-row top-5 keep, global max-normalize. Output dense [8192][8192] f32.
//
// R8: wave-per-row, zero barriers, NO register pair-arrays (R7's v_[36]/
// w_[36] spilled to scratch at VGPR=64 -> ~100us of scratch re-reads).
// Each bucket pass re-derives edges from uidx/val_e (L1-resident ~9KB).
// The row's zero-stores to out are issued FIRST so the 256MB write stream
// drains under the compute phase. k_norm splices normalized top-5 after.

#define EPSF 1e-8f
constexpr int U     = 8192;   // num_users
constexpr int NI    = 4096;   // num_items
constexpr int DEG   = 48;     // edges per item; edges grouped by item
constexpr int TOPK  = 5;
constexpr int MAXDU = 48;     // deg_u <= 48
constexpr int NT    = 256;
constexpr int WPB   = NT / 64;           // 4 waves (rows) per block
constexpr int SLOTS = 2048;              // bucket slots per wave (8KB)
constexpr int NPASS = U / SLOTS;         // 4 passes

typedef float f32x4 __attribute__((ext_vector_type(4)));

// descending sorted insert of (val,idx) into register 5-list (all static)
#define INS(val, idx)                                                         \
  if ((val) > v4) {                                                           \
    if ((val) > v2) {                                                         \
      if ((val) > v1) {                                                       \
        if ((val) > v0) { v4=v3;x4=x3; v3=v2;x3=x2; v2=v1;x2=x1; v1=v0;x1=x0; v0=(val);x0=(idx); } \
        else            { v4=v3;x4=x3; v3=v2;x3=x2; v2=v1;x2=x1; v1=(val);x1=(idx); }              \
      } else            { v4=v3;x4=x3; v3=v2;x3=x2; v2=(val);x2=(idx); }      \
    } else {                                                                  \
      if ((val) > v3)   { v4=v3;x4=x3; v3=(val);x3=(idx); }                   \
      else              { v4=(val);x4=(idx); }                                \
    }                                                                         \
  }

// ---------------------------------------------------------------- k_build
__global__ __launch_bounds__(NT) void k_build(
    const int* __restrict__ uidx, const int* __restrict__ iidx, int M,
    int* __restrict__ cnt, int* __restrict__ degi, int* __restrict__ items) {
  int e = blockIdx.x * NT + threadIdx.x;
  if (e >= M) return;
  int u = uidx[e];
  int j = iidx[e];
  atomicAdd(&degi[j], 1);
  int slot = atomicAdd(&cnt[u], 1);
  if (slot < MAXDU) items[u * MAXDU + slot] = j;
}

// -------------------------------------------------------------- k_scalars
__global__ __launch_bounds__(NT) void k_scalars(
    const int* __restrict__ cnt, const int* __restrict__ degi,
    const float* __restrict__ fraud_u, const float* __restrict__ theta,
    const float* __restrict__ gamma, float* __restrict__ a, float* __restrict__ t) {
  int i = blockIdx.x * NT + threadIdx.x;
  float g = gamma[0];
  if (i < U) {
    float su = log1pf((float)cnt[i]) * expf(g * fraud_u[i]);
    a[i] = sqrtf(su + EPSF);
  }
  if (i < NI) {
    float w  = log1pf(expf(theta[i])) + EPSF;   // softplus + EPS
    float si = log1pf((float)degi[i]);
    t[i] = (si + EPSF) * w;
  }
}

// ---------------------------------------------------------------- k_edges
// val_e[e] = t[i[e]] * a[u[e]]  (gathers done ONCE here, coalesced writes)
__global__ __launch_bounds__(NT) void k_edges(
    const int* __restrict__ uidx, const int* __restrict__ iidx, int M,
    const float* __restrict__ a, const float* __restrict__ t,
    float* __restrict__ val_e) {
  int e = blockIdx.x * NT + threadIdx.x;
  if (e >= M) return;
  val_e[e] = t[iidx[e]] * a[uidx[e]];
}

// ----------------------------------------------------------------- k_main
// Wave-per-row: stores first, then bucketed accumulate + top-5. No barriers.
__global__ __launch_bounds__(NT) void k_main(
    const int* __restrict__ uidx, const int* __restrict__ cnt,
    const int* __restrict__ items, const float* __restrict__ a,
    const float* __restrict__ val_e, float* __restrict__ val5,
    int* __restrict__ idx5, unsigned* __restrict__ gmax,
    float* __restrict__ out) {
  __shared__ float bkt[WPB][SLOTS];      // 8KB per wave, wave-private
  __shared__ int   shj[WPB][MAXDU];      // per-wave item list (pre-scaled *DEG)

  const int tid = threadIdx.x, lane = tid & 63, wid = tid >> 6;
  const int u = blockIdx.x * WPB + wid;
  float* B = bkt[wid];

  // ---- 1) issue the row's zero-stream NOW; drains under all later compute
  f32x4* orow = reinterpret_cast<f32x4*>(out + (size_t)u * U);
  f32x4 zz = {0.f, 0.f, 0.f, 0.f};
#pragma unroll
  for (int q = 0; q < U / 4 / 64; ++q)   // 32 chunks/lane, 1KB/instr coalesced
    __builtin_nontemporal_store(zz, &orow[q * 64 + lane]);

  // ---- 2) item list -> LDS (pre-scaled to edge base)
  int c = cnt[u]; if (c > MAXDU) c = MAXDU;
  if (lane < c) shj[wid][lane] = items[u * MAXDU + lane] * DEG;
  asm volatile("s_waitcnt lgkmcnt(0)" ::: "memory");  // shj visible (wave-local)

  const float au = a[u];
  const int total = c * DEG;
  float v0=-1.f,v1=-1.f,v2=-1.f,v3=-1.f,v4=-1.f;
  int   x0=-1,  x1=-1,  x2=-1,  x3=-1,  x4=-1;

  // ---- 3) 4 passes: zero -> scatter (re-derive edges) -> ownership scan
  for (int p = 0; p < NPASS; ++p) {
    const int base = p * SLOTS;
#pragma unroll
    for (int q = 0; q < SLOTS / 64; ++q) B[lane + 64 * q] = 0.f;
    asm volatile("s_waitcnt lgkmcnt(0)" ::: "memory");

    for (int x = lane; x < total; x += 64) {
      int k = x / DEG;                   // compile-time 48 -> magic-mul
      int e = shj[wid][k] + (x - k * DEG);
      int v = uidx[e];                   // L1-hot after pass 0 (~5KB/row)
      int d = v - base;
      if ((unsigned)d < (unsigned)SLOTS && v != u)
        atomicAdd(&B[d], val_e[e]);      // ds_add, wave-private region
    }
    asm volatile("s_waitcnt vmcnt(0) lgkmcnt(0)" ::: "memory");

#pragma unroll
    for (int q = 0; q < SLOTS / 64; ++q) {
      float s = B[lane + 64 * q];        // slot read by exactly one lane
      if (s > 0.f) { float val = au * s; INS(val, base + lane + 64 * q) }
    }
    asm volatile("s_waitcnt lgkmcnt(0)" ::: "memory");  // reads before re-zero
  }

  // ---- 4) wave top-5: 5 rounds of butterfly argmax over list heads
#pragma unroll
  for (int it = 0; it < TOPK; ++it) {
    float bv = v0; int bi = x0;
    for (int s = 32; s; s >>= 1) {
      float ov = __shfl_xor(bv, s);
      int   oi = __shfl_xor(bi, s);
      if (ov > bv || (ov == bv && oi < bi)) { bv = ov; bi = oi; }
    }
    if (bi >= 0 && x0 == bi) {           // pop winner (cols unique per wave)
      v0=v1;x0=x1; v1=v2;x1=x2; v2=v3;x2=x3; v3=v4;x3=x4; v4=-1.f;x4=-1;
    }
    if (lane == 0) {
      float sv = bv > 0.f ? bv : 0.f;
      val5[u * TOPK + it] = sv;
      idx5[u * TOPK + it] = bi;
      if (it == 0) atomicMax(gmax, __float_as_uint(sv));  // bits==float order
    }
  }
}

// ----------------------------------------------------------------- k_norm
// Splice the normalized kept values (<= 40960 scattered 4B stores).
__global__ __launch_bounds__(NT) void k_norm(
    const float* __restrict__ val5, const int* __restrict__ idx5,
    const unsigned* __restrict__ gmax, float* __restrict__ out) {
  int i = blockIdx.x * NT + threadIdx.x;
  if (i >= U * TOPK) return;
  int ix = idx5[i];
  float v = val5[i];
  if (ix >= 0 && v > 0.f) {
    float inv = 1.f / (__uint_as_float(*gmax) + EPSF);
    out[(size_t)(i / TOPK) * U + ix] = v * inv;
  }
}

// ------------------------------------------------------------------ host
extern "C" void kernel_launch(void* const* d_in, const int* in_sizes, int n_in,
                              void* d_out, int out_size, void* d_ws, size_t ws_size,
                              hipStream_t stream) {
  const int M = in_sizes[0] / 2;                    // 196608
  const int* uidx = (const int*)d_in[0];            // edge_index_ui row 0
  const int* iidx = uidx + M;                       // edge_index_ui row 1
  const float* fraud_u = (const float*)d_in[1];
  // d_in[2] fraud_i: unused (use_item_gamma=False)
  const float* theta = (const float*)d_in[3];
  const float* gamma = (const float*)d_in[4];

  int* ws = (int*)d_ws;
  int*      cnt   = ws;                             // [U]
  int*      degi  = ws + U;                         // [NI]
  unsigned* gmax  = (unsigned*)(ws + U + NI);       // [1] (+3 pad)
  float*    a     = (float*)(ws + U + NI + 4);      // [U]
  float*    t     = a + U;                          // [NI]
  float*    val5  = t + NI;                         // [U*TOPK]
  int*      idx5  = (int*)(val5 + U * TOPK);        // [U*TOPK]
  int*      items = idx5 + U * TOPK;                // [U*MAXDU]
  float*    val_e = (float*)(items + U * MAXDU);    // [M]
  float* out = (float*)d_out;

  (void)hipMemsetAsync(d_ws, 0, (size_t)(U + NI + 4) * sizeof(int), stream);
  k_build  <<<(M + NT - 1) / NT, NT, 0, stream>>>(uidx, iidx, M, cnt, degi, items);
  k_scalars<<<U / NT,            NT, 0, stream>>>(cnt, degi, fraud_u, theta, gamma, a, t);
  k_edges  <<<(M + NT - 1) / NT, NT, 0, stream>>>(uidx, iidx, M, a, t, val_e);
  k_main   <<<U / WPB,           NT, 0, stream>>>(uidx, cnt, items, a, val_e,
                                                  val5, idx5, gmax, out);
  k_norm   <<<(U * TOPK + NT - 1) / NT, NT, 0, stream>>>(val5, idx5, gmax, out);
}

// Round 9
// 197.421 us; speedup vs baseline: 1.2439x; 1.2439x over previous
//
#include <hip/hip_runtime.h>
#include <math.h>

// LearnableProjector: P[u,v] = a[u]*a[v]*sum_{j in common items} t[j];
// per-row top-5 keep, global max-normalize. Output dense [8192][8192] f32.
//
// R9: wave-per-row, zero barriers. The row's <=2304 (v,w) edge pairs are
// loaded from global ONCE into 72 NAMED scalar registers (pv0..35/pw0..35,
// no arrays -> no scratch). 4 bucket passes over 2048-column ranges are
// then pure LDS (zero -> ds_add scatter from regs -> b128 ownership scan).
// A quarter of the row's zero-stream is nt-stored after each pass; passes
// have no global loads, so stores never stall a wait. k_norm splices the
// normalized top-5 afterwards.

#define EPSF 1e-8f
constexpr int U     = 8192;   // num_users
constexpr int NI    = 4096;   // num_items
constexpr int DEG   = 48;     // edges per item; edges grouped by item
constexpr int TOPK  = 5;
constexpr int MAXDU = 48;     // deg_u <= 48
constexpr int NTB   = 256;    // block size for prep kernels
constexpr int NT    = 128;    // k_main: 2 waves per block
constexpr int WPB   = NT / 64;
constexpr int SLOTS = 2048;   // bucket slots per wave (8KB)

typedef float f32x4 __attribute__((ext_vector_type(4)));

// descending sorted insert of (val,idx) into register 5-list (tv*/ti*)
#define INS(val, idx)                                                         \
  if ((val) > tv4) {                                                          \
    if ((val) > tv2) {                                                        \
      if ((val) > tv1) {                                                      \
        if ((val) > tv0) { tv4=tv3;ti4=ti3; tv3=tv2;ti3=ti2; tv2=tv1;ti2=ti1; tv1=tv0;ti1=ti0; tv0=(val);ti0=(idx); } \
        else             { tv4=tv3;ti4=ti3; tv3=tv2;ti3=ti2; tv2=tv1;ti2=ti1; tv1=(val);ti1=(idx); }                   \
      } else             { tv4=tv3;ti4=ti3; tv3=tv2;ti3=ti2; tv2=(val);ti2=(idx); } \
    } else {                                                                  \
      if ((val) > tv3)   { tv4=tv3;ti4=ti3; tv3=(val);ti3=(idx); }            \
      else               { tv4=(val);ti4=(idx); }                             \
    }                                                                         \
  }

#define REP36(F) F(0)F(1)F(2)F(3)F(4)F(5)F(6)F(7)F(8)F(9)F(10)F(11)F(12)F(13)\
F(14)F(15)F(16)F(17)F(18)F(19)F(20)F(21)F(22)F(23)F(24)F(25)F(26)F(27)F(28)\
F(29)F(30)F(31)F(32)F(33)F(34)F(35)

// load pair r (named scalars; no arrays -> stays in VGPRs)
#define FILL(r) int pv##r = -1; float pw##r = 0.f;                            \
  { int x = lane + 64 * (r);                                                  \
    if (x < total) {                                                          \
      int k = x / DEG;                   /* compile-time 48 -> magic-mul */   \
      int e = shj[wid][k] + (x - k * DEG);                                    \
      int vv = uidx[e]; pw##r = val_e[e];                                     \
      if (vv != u) pv##r = vv; } }

// scatter pair r into this pass's bucket range (regs -> ds_add)
#define SCAT(r) { int d = pv##r - base;                                       \
  if ((unsigned)d < (unsigned)SLOTS) atomicAdd(&B[d], pw##r); }

// one bucket pass + its quarter of the zero-store stream
#define PASS(P) {                                                             \
  const int base = (P) * SLOTS;                                               \
  _Pragma("unroll") for (int q = 0; q < 8; ++q) Bv[lane + 64 * q] = zz4;      \
  asm volatile("s_waitcnt lgkmcnt(0)" ::: "memory");                          \
  REP36(SCAT)                                                                 \
  asm volatile("s_waitcnt lgkmcnt(0)" ::: "memory");                          \
  _Pragma("unroll") for (int q = 0; q < 8; ++q) {                             \
    f32x4 s4 = Bv[lane + 64 * q];                                             \
    int col0 = base + (lane + 64 * q) * 4;                                    \
    if (s4.x > 0.f) { float vl = au * s4.x; INS(vl, col0)     }               \
    if (s4.y > 0.f) { float vl = au * s4.y; INS(vl, col0 + 1) }               \
    if (s4.z > 0.f) { float vl = au * s4.z; INS(vl, col0 + 2) }               \
    if (s4.w > 0.f) { float vl = au * s4.w; INS(vl, col0 + 3) }               \
  }                                                                           \
  asm volatile("s_waitcnt lgkmcnt(0)" ::: "memory");                          \
  _Pragma("unroll") for (int q = 0; q < 8; ++q)                               \
    __builtin_nontemporal_store(zz4, &orow[(P) * 512 + lane + 64 * q]);       \
}

// ---------------------------------------------------------------- k_build
__global__ __launch_bounds__(NTB) void k_build(
    const int* __restrict__ uidx, const int* __restrict__ iidx, int M,
    int* __restrict__ cnt, int* __restrict__ degi, int* __restrict__ items) {
  int e = blockIdx.x * NTB + threadIdx.x;
  if (e >= M) return;
  int u = uidx[e];
  int j = iidx[e];
  atomicAdd(&degi[j], 1);
  int slot = atomicAdd(&cnt[u], 1);
  if (slot < MAXDU) items[u * MAXDU + slot] = j;
}

// -------------------------------------------------------------- k_scalars
__global__ __launch_bounds__(NTB) void k_scalars(
    const int* __restrict__ cnt, const int* __restrict__ degi,
    const float* __restrict__ fraud_u, const float* __restrict__ theta,
    const float* __restrict__ gamma, float* __restrict__ a, float* __restrict__ t) {
  int i = blockIdx.x * NTB + threadIdx.x;
  float g = gamma[0];
  if (i < U) {
    float su = log1pf((float)cnt[i]) * expf(g * fraud_u[i]);
    a[i] = sqrtf(su + EPSF);
  }
  if (i < NI) {
    float w  = log1pf(expf(theta[i])) + EPSF;   // softplus + EPS
    float si = log1pf((float)degi[i]);
    t[i] = (si + EPSF) * w;
  }
}

// ---------------------------------------------------------------- k_edges
__global__ __launch_bounds__(NTB) void k_edges(
    const int* __restrict__ uidx, const int* __restrict__ iidx, int M,
    const float* __restrict__ a, const float* __restrict__ t,
    float* __restrict__ val_e) {
  int e = blockIdx.x * NTB + threadIdx.x;
  if (e >= M) return;
  val_e[e] = t[iidx[e]] * a[uidx[e]];
}

// ----------------------------------------------------------------- k_main
__global__ __launch_bounds__(NT, 2) void k_main(
    const int* __restrict__ uidx, const int* __restrict__ cnt,
    const int* __restrict__ items, const float* __restrict__ a,
    const float* __restrict__ val_e, float* __restrict__ val5,
    int* __restrict__ idx5, unsigned* __restrict__ gmax,
    float* __restrict__ out) {
  __shared__ float bkt[WPB][SLOTS];      // 8KB per wave, wave-private
  __shared__ int   shj[WPB][MAXDU];      // item list, pre-scaled *DEG

  const int tid = threadIdx.x, lane = tid & 63, wid = tid >> 6;
  const int u = blockIdx.x * WPB + wid;
  float* B  = bkt[wid];
  f32x4* Bv = reinterpret_cast<f32x4*>(B);
  f32x4* orow = reinterpret_cast<f32x4*>(out + (size_t)u * U);
  const f32x4 zz4 = {0.f, 0.f, 0.f, 0.f};

  int c = cnt[u]; if (c > MAXDU) c = MAXDU;
  if (lane < c) shj[wid][lane] = items[u * MAXDU + lane] * DEG;
  const int total = c * DEG;
  const float au = a[u];

  // ---- load all pairs ONCE into named registers (coalesced by item)
  REP36(FILL)

  float tv0=-1.f,tv1=-1.f,tv2=-1.f,tv3=-1.f,tv4=-1.f;
  int   ti0=-1,  ti1=-1,  ti2=-1,  ti3=-1,  ti4=-1;

  // ---- 4 LDS-only passes; quarter of the zero-stream after each
  PASS(0) PASS(1) PASS(2) PASS(3)

  // ---- wave top-5: 5 rounds of butterfly argmax over sorted-list heads
#pragma unroll
  for (int it = 0; it < TOPK; ++it) {
    float bv = tv0; int bi = ti0;
    for (int s = 32; s; s >>= 1) {
      float ov = __shfl_xor(bv, s);
      int   oi = __shfl_xor(bi, s);
      if (ov > bv || (ov == bv && oi < bi)) { bv = ov; bi = oi; }
    }
    if (bi >= 0 && ti0 == bi) {          // pop winner (cols unique per wave)
      tv0=tv1;ti0=ti1; tv1=tv2;ti1=ti2; tv2=tv3;ti2=ti3; tv3=tv4;ti3=ti4;
      tv4=-1.f;ti4=-1;
    }
    if (lane == 0) {
      float sv = bv > 0.f ? bv : 0.f;
      val5[u * TOPK + it] = sv;
      idx5[u * TOPK + it] = bi;
      if (it == 0) atomicMax(gmax, __float_as_uint(sv));  // bits==float order
    }
  }
}

// ----------------------------------------------------------------- k_norm
__global__ __launch_bounds__(NTB) void k_norm(
    const float* __restrict__ val5, const int* __restrict__ idx5,
    const unsigned* __restrict__ gmax, float* __restrict__ out) {
  int i = blockIdx.x * NTB + threadIdx.x;
  if (i >= U * TOPK) return;
  int ix = idx5[i];
  float v = val5[i];
  if (ix >= 0 && v > 0.f) {
    float inv = 1.f / (__uint_as_float(*gmax) + EPSF);
    out[(size_t)(i / TOPK) * U + ix] = v * inv;
  }
}

// ------------------------------------------------------------------ host
extern "C" void kernel_launch(void* const* d_in, const int* in_sizes, int n_in,
                              void* d_out, int out_size, void* d_ws, size_t ws_size,
                              hipStream_t stream) {
  const int M = in_sizes[0] / 2;                    // 196608
  const int* uidx = (const int*)d_in[0];            // edge_index_ui row 0
  const int* iidx = uidx + M;                       // edge_index_ui row 1
  const float* fraud_u = (const float*)d_in[1];
  // d_in[2] fraud_i: unused (use_item_gamma=False)
  const float* theta = (const float*)d_in[3];
  const float* gamma = (const float*)d_in[4];

  int* ws = (int*)d_ws;
  int*      cnt   = ws;                             // [U]
  int*      degi  = ws + U;                         // [NI]
  unsigned* gmax  = (unsigned*)(ws + U + NI);       // [1] (+3 pad)
  float*    a     = (float*)(ws + U + NI + 4);      // [U]
  float*    t     = a + U;                          // [NI]
  float*    val5  = t + NI;                         // [U*TOPK]
  int*      idx5  = (int*)(val5 + U * TOPK);        // [U*TOPK]
  int*      items = idx5 + U * TOPK;                // [U*MAXDU]
  float*    val_e = (float*)(items + U * MAXDU);    // [M]
  float* out = (float*)d_out;

  (void)hipMemsetAsync(d_ws, 0, (size_t)(U + NI + 4) * sizeof(int), stream);
  k_build  <<<(M + NTB - 1) / NTB, NTB, 0, stream>>>(uidx, iidx, M, cnt, degi, items);
  k_scalars<<<U / NTB,             NTB, 0, stream>>>(cnt, degi, fraud_u, theta, gamma, a, t);
  k_edges  <<<(M + NTB - 1) / NTB, NTB, 0, stream>>>(uidx, iidx, M, a, t, val_e);
  k_main   <<<U / WPB,             NT,  0, stream>>>(uidx, cnt, items, a, val_e,
                                                     val5, idx5, gmax, out);
  k_norm   <<<(U * TOPK + NTB - 1) / NTB, NTB, 0, stream>>>(val5, idx5, gmax, out);
}